// Round 3
// baseline (1411.134 us; speedup 1.0000x reference)
//
#include <hip/hip_runtime.h>
#include <stdint.h>

#define DD   128   // D
#define G2D  256   // 2*D
#define G4D  512   // 4*D
#define GPB  8     // graphs per block
#define SLOT 64    // LDS node-row slots per graph
#define ASTR 264   // padded stride (shorts) of A tile

typedef float  f32x4  __attribute__((ext_vector_type(4)));
typedef short  s16x4  __attribute__((ext_vector_type(4)));
typedef short  s16x8  __attribute__((ext_vector_type(8)));
typedef int    i32x4  __attribute__((ext_vector_type(4)));
typedef __bf16 bf16x8 __attribute__((ext_vector_type(8)));

__device__ __forceinline__ short f2bf(float f) {
  unsigned u = __builtin_bit_cast(unsigned, f);
  u += 0x7FFFu + ((u >> 16) & 1u);   // RNE
  return (short)(u >> 16);
}
__device__ __forceinline__ void unpack2(int w_, float& lo, float& hi) {
  lo = __builtin_bit_cast(float, (int)(w_ << 16));
  hi = __builtin_bit_cast(float, (int)(w_ & 0xFFFF0000));
}
__device__ __forceinline__ float sigmoidf_(float x) {
  return 1.f / (1.f + __expf(-x));
}
__device__ __forceinline__ float tanhf_(float x) {
  x = fminf(fmaxf(x, -15.f), 15.f);
  float e = __expf(2.f * x);
  return (e - 1.f) / (e + 1.f);
}

// all-lanes sum within each 16-lane row via DPP row_ror (no LDS round-trips)
template <int CTRL>
__device__ __forceinline__ float dppadd_(float v) {
  const int x = __builtin_amdgcn_update_dpp(
      0, __builtin_bit_cast(int, v), CTRL, 0xF, 0xF, true);
  return v + __builtin_bit_cast(float, x);
}
__device__ __forceinline__ float reduce16(float v) {
  v = dppadd_<0x128>(v);   // row_ror:8
  v = dppadd_<0x124>(v);   // row_ror:4
  v = dppadd_<0x122>(v);   // row_ror:2
  v = dppadd_<0x121>(v);   // row_ror:1
  return v;
}

// seg[g] = lower_bound(ind, g) for g in [0..G]; graph_indicator is sorted.
__global__ void seg_kernel(const int* __restrict__ ind, int* __restrict__ seg,
                           int N, int G) {
  int g = blockIdx.x * blockDim.x + threadIdx.x;
  if (g > G) return;
  int lo = 0, hi = N;
  while (lo < hi) {
    int mid = (lo + hi) >> 1;
    if (ind[mid] < g) lo = mid + 1; else hi = mid;
  }
  seg[g] = lo;
}

// WT[n][k] = bf16(W[k][n]); W is [256,512] fp32, WT is [512,256] bf16
__global__ void wconv_kernel(const float* __restrict__ W, short* __restrict__ WT) {
  int idx = blockIdx.x * blockDim.x + threadIdx.x;  // 131072 threads
  int n = idx & (G4D - 1);
  int k = idx >> 9;
  WT[(size_t)n * G2D + k] = f2bf(W[(size_t)k * G4D + n]);
}

// Fully fused: 8 graphs / 1024-thread block (2 waves per graph), all 8 steps.
// Phase A: wave pair splits rows; DPP dot-reduce; defer-max online softmax;
// cross-wave merge via LDS. Phase B: each wave caches 2 gate col-tiles of W
// in 64 VGPRs; wp1 ships its gate tiles to wp0 via LDS z-buffer for epilogue.
__global__ void __launch_bounds__(1024) fused_kernel(
    const float* __restrict__ nf, const int* __restrict__ seg,
    const short* __restrict__ WT, const float* __restrict__ bias,
    float* __restrict__ out, int G) {
  extern __shared__ char smem[];
  short* nfb   = (short*)smem;                                // [GPB][SLOT][DD]
  short* A     = (short*)(smem + GPB * SLOT * DD * 2);        // [16][ASTR]
  float* carry = (float*)(smem + GPB * SLOT * DD * 2 + 16 * ASTR * 2);
  float* mem   = carry + GPB * DD;
  float* xbuf  = mem + GPB * DD;    // 8192 B: softmax partials / z-exchange

  const int t    = threadIdx.x;
  const int w    = t >> 6;
  const int lane = t & 63;
  const int gq   = lane >> 4;      // group / MFMA quad
  const int sl   = lane & 15;      // sub-lane / MFMA l16
  const int gl   = w >> 1;         // local graph id == col-tile id (0..7)
  const int wp   = w & 1;          // wave-in-pair
  const int g0   = blockIdx.x * GPB;
  const int g    = g0 + gl;
  const bool active = (g < G);

  // ---- init ----
  {
    int* az = (int*)A;
    for (int i = t; i < (16 * ASTR) / 2; i += 1024) az[i] = 0;
    if (t < GPB * DD) { mem[t] = 0.f; carry[t] = 0.f; }
  }
  int s0 = 0, n = 0;
  if (active) { s0 = seg[g]; n = seg[g + 1] - s0; }

  // ---- stage rows into LDS (pair covers 4 rows/iter), depth-2 pipeline ----
  short* slot = nfb + gl * (SLOT * DD);
  const int nl = n < SLOT ? n : SLOT;
  {
    const int r4 = (wp << 1) | (lane >> 5);   // 0..3
    const int c  = lane & 31;                 // f32x4 index in row
    f32x4 vc; int rowc = r4; bool okc = rowc < nl;
    if (okc) vc = *((const f32x4*)(nf + (size_t)(s0 + rowc) * DD) + c);
    const int iters = (nl + 3) >> 2;
    for (int i = 0; i < iters; ++i) {
      const int rown = (i + 1) * 4 + r4;
      f32x4 vn; const bool okn = rown < nl;
      if (okn) vn = *((const f32x4*)(nf + (size_t)(s0 + rown) * DD) + c);
      if (okc) {
        s16x4 o;
        o[0] = f2bf(vc.x); o[1] = f2bf(vc.y); o[2] = f2bf(vc.z); o[3] = f2bf(vc.w);
        *(s16x4*)(slot + (size_t)rowc * DD + c * 4) = o;
      }
      vc = vn; rowc = rown; okc = okn;
    }
  }

  // ---- per-wave W cache: 2 gates x 8 kc (64 VGPRs). wp0: u,f; wp1: c,o ----
  s16x8 bw[8][2];
  #pragma unroll
  for (int kc = 0; kc < 8; ++kc)
    #pragma unroll
    for (int j = 0; j < 2; ++j) {
      const int ncol = (wp * 2 + j) * DD + gl * 16 + sl;
      bw[kc][j] = *(const s16x8*)(WT + (size_t)ncol * G2D + kc * 32 + gq * 8);
    }
  const int colB = gl * 16 + sl;
  const float bU = bias[colB],          bF = bias[DD + colB],
              bC = bias[2 * DD + colB], bO = bias[3 * DD + colB];

  __syncthreads();   // staging + zero-init visible to everyone

  #pragma unroll 1
  for (int step = 0; step < 8; ++step) {
    const bool noscore = (step == 0);   // carry==0 -> all scores 0 -> mean pool
    const f32x4 c0 = *(const f32x4*)(carry + gl * DD + sl * 8);
    const f32x4 c1 = *(const f32x4*)(carry + gl * DD + sl * 8 + 4);

    // ============ Phase A: attention readout (pair-split rows) ============
    float m = -1e30f, l = 0.f, acc[8];
    #pragma unroll
    for (int k = 0; k < 8; ++k) acc[k] = 0.f;
    const int off = wp * 4 + gq;        // row stream id (0..7)

    auto score = [&](const float xf[8]) -> float {
      float a = fmaf(xf[1], c0.y, xf[0] * c0.x);
      float b = fmaf(xf[3], c0.w, xf[2] * c0.z);
      float c = fmaf(xf[5], c1.y, xf[4] * c1.x);
      float d = fmaf(xf[7], c1.w, xf[6] * c1.z);
      return reduce16((a + b) + (c + d));
    };
    auto upd = [&](const float xf[8], float s) {
      if (s > m + 8.f) {                 // rare: raise reference, rescale
        const float sc = __expf(m - s);  // exp(-huge)=0 on first row
        l *= sc;
        #pragma unroll
        for (int k = 0; k < 8; ++k) acc[k] *= sc;
        m = s;
      }
      const float p = __expf(s - m);     // bounded by e^8
      l += p;
      #pragma unroll
      for (int k = 0; k < 8; ++k) acc[k] = fmaf(p, xf[k], acc[k]);
    };

    if (active && n > 0) {
      const short* bp = slot + (size_t)off * DD + sl * 8;
      const int nfull = nl >> 3;
      i32x4 xr;
      if (nfull > 0) xr = *(const i32x4*)bp;
      for (int i = 0; i < nfull; ++i) {
        i32x4 xn = *(const i32x4*)(bp + (size_t)(i + 1) * 8 * DD); // prefetch (overrun benign, in-LDS)
        float xf[8];
        unpack2(xr.x, xf[0], xf[1]); unpack2(xr.y, xf[2], xf[3]);
        unpack2(xr.z, xf[4], xf[5]); unpack2(xr.w, xf[6], xf[7]);
        const float s = noscore ? 0.f : score(xf);
        upd(xf, s);
        xr = xn;
      }
      const int rem = nl & 7;
      if (off < rem) {
        const i32x4 xv = *(const i32x4*)(bp + (size_t)nfull * 8 * DD);
        float xf[8];
        unpack2(xv.x, xf[0], xf[1]); unpack2(xv.y, xf[2], xf[3]);
        unpack2(xv.z, xf[4], xf[5]); unpack2(xv.w, xf[6], xf[7]);
        const float s = noscore ? 0.f : score(xf);
        upd(xf, s);
      }
      for (int j = SLOT + off; j < n; j += 8) {     // overflow rows (rare)
        const f32x4* gp = (const f32x4*)(nf + (size_t)(s0 + j) * DD) + sl * 2;
        const f32x4 a = gp[0], b = gp[1];
        const float xf[8] = {a.x, a.y, a.z, a.w, b.x, b.y, b.z, b.w};
        const float s = noscore ? 0.f : score(xf);
        upd(xf, s);
      }
      // intra-wave merge of the 4 groups (xor16, xor32)
      #pragma unroll
      for (int ww = 16; ww <= 32; ww <<= 1) {
        const float m2 = __shfl_xor(m, ww, 64);
        const float l2 = __shfl_xor(l, ww, 64);
        const float M  = fmaxf(m, m2);
        const float e1 = __expf(m - M), e2 = __expf(m2 - M);
        l = l * e1 + l2 * e2;
        #pragma unroll
        for (int k = 0; k < 8; ++k)
          acc[k] = acc[k] * e1 + __shfl_xor(acc[k], ww, 64) * e2;
        m = M;
      }
    }

    // ---- cross-wave merge through LDS ----
    float* xb = xbuf + (gl * 16 + sl) * 12;
    if (wp == 1 && gq == 0) {
      *(f32x4*)(xb)     = (f32x4){acc[0], acc[1], acc[2], acc[3]};
      *(f32x4*)(xb + 4) = (f32x4){acc[4], acc[5], acc[6], acc[7]};
      xb[8] = m; xb[9] = l;
    }
    __syncthreads();   // s1: partials visible
    if (wp == 0 && gq == 0) {
      const float m2 = xb[8], l2 = xb[9];
      const f32x4 a0 = *(const f32x4*)xb, a1 = *(const f32x4*)(xb + 4);
      const float a2[8] = {a0.x, a0.y, a0.z, a0.w, a1.x, a1.y, a1.z, a1.w};
      const float M  = fmaxf(m, m2);
      const float e1 = __expf(m - M), e2 = __expf(m2 - M);
      const float L  = l * e1 + l2 * e2;
      const float inv = (L > 0.f) ? 1.f / L : 0.f;
      float r[8];
      s16x8 pk;
      #pragma unroll
      for (int k = 0; k < 8; ++k) {
        r[k]  = (acc[k] * e1 + a2[k] * e2) * inv;
        pk[k] = f2bf(r[k]);
      }
      *(s16x8*)(A + gl * ASTR + DD + sl * 8) = pk;   // readout half of A row
      if (step == 7 && active) {
        *(f32x4*)(out + (size_t)g * G2D + DD + sl * 8)     = (f32x4){r[0], r[1], r[2], r[3]};
        *(f32x4*)(out + (size_t)g * G2D + DD + sl * 8 + 4) = (f32x4){r[4], r[5], r[6], r[7]};
      }
    }
    if (step == 7) {
      if (wp == 0 && gq == 1 && active) {   // carry half (state after step 6)
        *(f32x4*)(out + (size_t)g * G2D + sl * 8) =
            *(const f32x4*)(carry + gl * DD + sl * 8);
        *(f32x4*)(out + (size_t)g * G2D + sl * 8 + 4) =
            *(const f32x4*)(carry + gl * DD + sl * 8 + 4);
      }
      break;
    }
    __syncthreads();   // s2: A readout visible for MFMA

    // ============ Phase B: batched LSTM via MFMA (2 gates/wave) ============
    f32x4 az[2] = {(f32x4){0.f, 0.f, 0.f, 0.f}, (f32x4){0.f, 0.f, 0.f, 0.f}};
    #pragma unroll
    for (int kc = 0; kc < 8; ++kc) {
      const s16x8 af = *(const s16x8*)(A + (size_t)sl * ASTR + kc * 32 + gq * 8);
      #pragma unroll
      for (int j = 0; j < 2; ++j)
        az[j] = __builtin_amdgcn_mfma_f32_16x16x32_bf16(
            __builtin_bit_cast(bf16x8, af), __builtin_bit_cast(bf16x8, bw[kc][j]),
            az[j], 0, 0, 0);
    }
    // wp1 ships its gate tiles (c,o) to wp0 through the shared buffer
    if (wp == 1 && gq < 2) {
      #pragma unroll
      for (int j = 0; j < 2; ++j)
        #pragma unroll
        for (int rr = 0; rr < 4; ++rr) {
          const int row = gq * 4 + rr;           // local graph 0..7
          xbuf[((gl * 2 + j) * 8 + row) * 16 + sl] = az[j][rr];
        }
    }
    __syncthreads();   // s3: z tiles visible; A reads complete
    if (wp == 0 && gq < 2) {
      #pragma unroll
      for (int rr = 0; rr < 4; ++rr) {
        const int row = gq * 4 + rr;
        if (g0 + row < G) {
          const float u  = az[0][rr] + bU;
          const float f  = az[1][rr] + bF;
          const float c  = xbuf[((gl * 2 + 0) * 8 + row) * 16 + sl] + bC;
          const float o  = xbuf[((gl * 2 + 1) * 8 + row) * 16 + sl] + bO;
          const float mo = mem[row * DD + colB];
          const float mn = sigmoidf_(f) * mo + sigmoidf_(u) * tanhf_(c);
          mem[row * DD + colB] = mn;
          const float cn = sigmoidf_(o) * tanhf_(mn);
          carry[row * DD + colB] = cn;       // f32 state for next score pass
          A[row * ASTR + colB] = f2bf(cn);   // bf16 carry half of next A
        }
      }
    }
    __syncthreads();   // s4: state update visible before next phase A
  }
}

extern "C" void kernel_launch(void* const* d_in, const int* in_sizes, int n_in,
                              void* d_out, int out_size, void* d_ws, size_t ws_size,
                              hipStream_t stream) {
  const float* nf   = (const float*)d_in[0];
  const int*   ind  = (const int*)d_in[1];
  const float* W    = (const float*)d_in[2];
  const float* bias = (const float*)d_in[3];
  int N = in_sizes[1];
  int G = out_size / G2D;   // 25000

  char* ws = (char*)d_ws;
  short* WT  = (short*)ws;                       // 512*256*2 = 262144 B
  int*   seg = (int*)(ws + 262144);              // (G+1)*4 B
  (void)ws_size; (void)n_in;

  seg_kernel<<<(G + 256) / 256, 256, 0, stream>>>(ind, seg, N, G);
  wconv_kernel<<<(G2D * G4D) / 256, 256, 0, stream>>>(W, WT);

  const int SMEM_BYTES = GPB * SLOT * DD * 2     // 131072  nf tile
                       + 16 * ASTR * 2           //   8448  A tile
                       + GPB * DD * 4            //   4096  carry
                       + GPB * DD * 4            //   4096  mem
                       + 8192;                   //   xbuf/zbuf  => 155904
  static bool attr_set = false;
  if (!attr_set) {
    hipFuncSetAttribute(reinterpret_cast<const void*>(fused_kernel),
                        hipFuncAttributeMaxDynamicSharedMemorySize, SMEM_BYTES);
    attr_set = true;
  }
  fused_kernel<<<(G + GPB - 1) / GPB, 1024, SMEM_BYTES, stream>>>(
      nf, seg, WT, bias, (float*)d_out, G);
}

// Round 4
// 1405.891 us; speedup vs baseline: 1.0037x; 1.0037x over previous
//
#include <hip/hip_runtime.h>
#include <stdint.h>

#define DD   128   // D
#define G2D  256   // 2*D
#define G4D  512   // 4*D
#define GPB  8     // graphs per block
#define SLOT 64    // LDS node-row slots per graph
#define ASTR 264   // padded stride (shorts) of A tile

typedef float  f32x4  __attribute__((ext_vector_type(4)));
typedef short  s16x4  __attribute__((ext_vector_type(4)));
typedef short  s16x8  __attribute__((ext_vector_type(8)));
typedef int    i32x4  __attribute__((ext_vector_type(4)));
typedef __bf16 bf16x8 __attribute__((ext_vector_type(8)));

__device__ __forceinline__ short f2bf(float f) {
  unsigned u = __builtin_bit_cast(unsigned, f);
  u += 0x7FFFu + ((u >> 16) & 1u);   // RNE
  return (short)(u >> 16);
}
__device__ __forceinline__ void unpack2(int w_, float& lo, float& hi) {
  lo = __builtin_bit_cast(float, (int)(w_ << 16));
  hi = __builtin_bit_cast(float, (int)(w_ & 0xFFFF0000));
}
__device__ __forceinline__ float sigmoidf_(float x) {
  return 1.f / (1.f + __expf(-x));
}
__device__ __forceinline__ float tanhf_(float x) {
  x = fminf(fmaxf(x, -15.f), 15.f);
  float e = __expf(2.f * x);
  return (e - 1.f) / (e + 1.f);
}

// all-lanes sum within each 16-lane row via DPP row_ror (no LDS round-trips)
template <int CTRL>
__device__ __forceinline__ float dppadd_(float v) {
  const int x = __builtin_amdgcn_update_dpp(
      0, __builtin_bit_cast(int, v), CTRL, 0xF, 0xF, true);
  return v + __builtin_bit_cast(float, x);
}
__device__ __forceinline__ float reduce16(float v) {
  v = dppadd_<0x128>(v);   // row_ror:8
  v = dppadd_<0x124>(v);   // row_ror:4
  v = dppadd_<0x122>(v);   // row_ror:2
  v = dppadd_<0x121>(v);   // row_ror:1
  return v;
}

// seg[g] = lower_bound(ind, g) for g in [0..G]; graph_indicator is sorted.
__global__ void seg_kernel(const int* __restrict__ ind, int* __restrict__ seg,
                           int N, int G) {
  int g = blockIdx.x * blockDim.x + threadIdx.x;
  if (g > G) return;
  int lo = 0, hi = N;
  while (lo < hi) {
    int mid = (lo + hi) >> 1;
    if (ind[mid] < g) lo = mid + 1; else hi = mid;
  }
  seg[g] = lo;
}

// WT[n][k] = bf16(W[k][n]); W is [256,512] fp32, WT is [512,256] bf16
__global__ void wconv_kernel(const float* __restrict__ W, short* __restrict__ WT) {
  int idx = blockIdx.x * blockDim.x + threadIdx.x;  // 131072 threads
  int n = idx & (G4D - 1);
  int k = idx >> 9;
  WT[(size_t)n * G2D + k] = f2bf(W[(size_t)k * G4D + n]);
}

// Fully fused: 8 graphs / 1024-thread block (2 waves per graph), all 8 steps.
// __launch_bounds__(1024, 4): 4 waves/EU => VGPR cap 128 (64-cap spilled ~275MB
// to scratch in the previous round; this is the A/B fix).
__global__ void __launch_bounds__(1024, 4) fused_kernel(
    const float* __restrict__ nf, const int* __restrict__ seg,
    const short* __restrict__ WT, const float* __restrict__ bias,
    float* __restrict__ out, int G) {
  extern __shared__ char smem[];
  short* nfb   = (short*)smem;                                // [GPB][SLOT][DD]
  short* A     = (short*)(smem + GPB * SLOT * DD * 2);        // [16][ASTR]
  float* carry = (float*)(smem + GPB * SLOT * DD * 2 + 16 * ASTR * 2);
  float* mem   = carry + GPB * DD;
  float* xbuf  = mem + GPB * DD;    // 8192 B: softmax partials / z-exchange

  const int t    = threadIdx.x;
  const int w    = t >> 6;
  const int lane = t & 63;
  const int gq   = lane >> 4;      // group / MFMA quad
  const int sl   = lane & 15;      // sub-lane / MFMA l16
  const int gl   = w >> 1;         // local graph id == col-tile id (0..7)
  const int wp   = w & 1;          // wave-in-pair
  const int g0   = blockIdx.x * GPB;
  const int g    = g0 + gl;
  const bool active = (g < G);

  // ---- init ----
  {
    int* az = (int*)A;
    for (int i = t; i < (16 * ASTR) / 2; i += 1024) az[i] = 0;
    if (t < GPB * DD) { mem[t] = 0.f; carry[t] = 0.f; }
  }
  int s0 = 0, n = 0;
  if (active) { s0 = seg[g]; n = seg[g + 1] - s0; }

  // ---- stage rows into LDS (pair covers 4 rows/iter), depth-2 pipeline ----
  short* slot = nfb + gl * (SLOT * DD);
  const int nl = n < SLOT ? n : SLOT;
  {
    const int r4 = (wp << 1) | (lane >> 5);   // 0..3
    const int c  = lane & 31;                 // f32x4 index in row
    f32x4 vc; int rowc = r4; bool okc = rowc < nl;
    if (okc) vc = *((const f32x4*)(nf + (size_t)(s0 + rowc) * DD) + c);
    const int iters = (nl + 3) >> 2;
    for (int i = 0; i < iters; ++i) {
      const int rown = (i + 1) * 4 + r4;
      f32x4 vn; const bool okn = rown < nl;
      if (okn) vn = *((const f32x4*)(nf + (size_t)(s0 + rown) * DD) + c);
      if (okc) {
        s16x4 o;
        o[0] = f2bf(vc.x); o[1] = f2bf(vc.y); o[2] = f2bf(vc.z); o[3] = f2bf(vc.w);
        *(s16x4*)(slot + (size_t)rowc * DD + c * 4) = o;
      }
      vc = vn; rowc = rown; okc = okn;
    }
  }

  // ---- per-wave W cache: 2 gates x 8 kc (64 VGPRs). wp0: u,f; wp1: c,o ----
  s16x8 bw[8][2];
  #pragma unroll
  for (int kc = 0; kc < 8; ++kc)
    #pragma unroll
    for (int j = 0; j < 2; ++j) {
      const int ncol = (wp * 2 + j) * DD + gl * 16 + sl;
      bw[kc][j] = *(const s16x8*)(WT + (size_t)ncol * G2D + kc * 32 + gq * 8);
    }
  const int colB = gl * 16 + sl;
  const float bU = bias[colB],          bF = bias[DD + colB],
              bC = bias[2 * DD + colB], bO = bias[3 * DD + colB];

  __syncthreads();   // staging + zero-init visible to everyone

  #pragma unroll 1
  for (int step = 0; step < 8; ++step) {
    const bool noscore = (step == 0);   // carry==0 -> all scores 0 -> mean pool
    const f32x4 c0 = *(const f32x4*)(carry + gl * DD + sl * 8);
    const f32x4 c1 = *(const f32x4*)(carry + gl * DD + sl * 8 + 4);

    // ============ Phase A: attention readout (pair-split rows) ============
    float m = -1e30f, l = 0.f, acc[8];
    #pragma unroll
    for (int k = 0; k < 8; ++k) acc[k] = 0.f;
    const int off = wp * 4 + gq;        // row stream id (0..7)

    auto score = [&](const float xf[8]) -> float {
      float a = fmaf(xf[1], c0.y, xf[0] * c0.x);
      float b = fmaf(xf[3], c0.w, xf[2] * c0.z);
      float c = fmaf(xf[5], c1.y, xf[4] * c1.x);
      float d = fmaf(xf[7], c1.w, xf[6] * c1.z);
      return reduce16((a + b) + (c + d));
    };
    auto upd = [&](const float xf[8], float s) {
      if (s > m + 8.f) {                 // rare: raise reference, rescale
        const float sc = __expf(m - s);  // exp(-huge)=0 on first row
        l *= sc;
        #pragma unroll
        for (int k = 0; k < 8; ++k) acc[k] *= sc;
        m = s;
      }
      const float p = __expf(s - m);     // bounded by e^8
      l += p;
      #pragma unroll
      for (int k = 0; k < 8; ++k) acc[k] = fmaf(p, xf[k], acc[k]);
    };

    if (active && n > 0) {
      const short* bp = slot + (size_t)off * DD + sl * 8;
      const int nfull = nl >> 3;
      i32x4 xr;
      if (nfull > 0) xr = *(const i32x4*)bp;
      for (int i = 0; i < nfull; ++i) {
        i32x4 xn = *(const i32x4*)(bp + (size_t)(i + 1) * 8 * DD); // prefetch (overrun benign, in-LDS)
        float xf[8];
        unpack2(xr.x, xf[0], xf[1]); unpack2(xr.y, xf[2], xf[3]);
        unpack2(xr.z, xf[4], xf[5]); unpack2(xr.w, xf[6], xf[7]);
        const float s = noscore ? 0.f : score(xf);
        upd(xf, s);
        xr = xn;
      }
      const int rem = nl & 7;
      if (off < rem) {
        const i32x4 xv = *(const i32x4*)(bp + (size_t)nfull * 8 * DD);
        float xf[8];
        unpack2(xv.x, xf[0], xf[1]); unpack2(xv.y, xf[2], xf[3]);
        unpack2(xv.z, xf[4], xf[5]); unpack2(xv.w, xf[6], xf[7]);
        const float s = noscore ? 0.f : score(xf);
        upd(xf, s);
      }
      for (int j = SLOT + off; j < n; j += 8) {     // overflow rows (rare)
        const f32x4* gp = (const f32x4*)(nf + (size_t)(s0 + j) * DD) + sl * 2;
        const f32x4 a = gp[0], b = gp[1];
        const float xf[8] = {a.x, a.y, a.z, a.w, b.x, b.y, b.z, b.w};
        const float s = noscore ? 0.f : score(xf);
        upd(xf, s);
      }
      // intra-wave merge of the 4 groups (xor16, xor32)
      #pragma unroll
      for (int ww = 16; ww <= 32; ww <<= 1) {
        const float m2 = __shfl_xor(m, ww, 64);
        const float l2 = __shfl_xor(l, ww, 64);
        const float M  = fmaxf(m, m2);
        const float e1 = __expf(m - M), e2 = __expf(m2 - M);
        l = l * e1 + l2 * e2;
        #pragma unroll
        for (int k = 0; k < 8; ++k)
          acc[k] = acc[k] * e1 + __shfl_xor(acc[k], ww, 64) * e2;
        m = M;
      }
    }

    // ---- cross-wave merge through LDS ----
    float* xb = xbuf + (gl * 16 + sl) * 12;
    if (wp == 1 && gq == 0) {
      *(f32x4*)(xb)     = (f32x4){acc[0], acc[1], acc[2], acc[3]};
      *(f32x4*)(xb + 4) = (f32x4){acc[4], acc[5], acc[6], acc[7]};
      xb[8] = m; xb[9] = l;
    }
    __syncthreads();   // s1: partials visible
    if (wp == 0 && gq == 0) {
      const float m2 = xb[8], l2 = xb[9];
      const f32x4 a0 = *(const f32x4*)xb, a1 = *(const f32x4*)(xb + 4);
      const float a2[8] = {a0.x, a0.y, a0.z, a0.w, a1.x, a1.y, a1.z, a1.w};
      const float M  = fmaxf(m, m2);
      const float e1 = __expf(m - M), e2 = __expf(m2 - M);
      const float L  = l * e1 + l2 * e2;
      const float inv = (L > 0.f) ? 1.f / L : 0.f;
      float r[8];
      s16x8 pk;
      #pragma unroll
      for (int k = 0; k < 8; ++k) {
        r[k]  = (acc[k] * e1 + a2[k] * e2) * inv;
        pk[k] = f2bf(r[k]);
      }
      *(s16x8*)(A + gl * ASTR + DD + sl * 8) = pk;   // readout half of A row
      if (step == 7 && active) {
        *(f32x4*)(out + (size_t)g * G2D + DD + sl * 8)     = (f32x4){r[0], r[1], r[2], r[3]};
        *(f32x4*)(out + (size_t)g * G2D + DD + sl * 8 + 4) = (f32x4){r[4], r[5], r[6], r[7]};
      }
    }
    if (step == 7) {
      if (wp == 0 && gq == 1 && active) {   // carry half (state after step 6)
        *(f32x4*)(out + (size_t)g * G2D + sl * 8) =
            *(const f32x4*)(carry + gl * DD + sl * 8);
        *(f32x4*)(out + (size_t)g * G2D + sl * 8 + 4) =
            *(const f32x4*)(carry + gl * DD + sl * 8 + 4);
      }
      break;
    }
    __syncthreads();   // s2: A readout visible for MFMA

    // ============ Phase B: batched LSTM via MFMA (2 gates/wave) ============
    f32x4 az[2] = {(f32x4){0.f, 0.f, 0.f, 0.f}, (f32x4){0.f, 0.f, 0.f, 0.f}};
    #pragma unroll
    for (int kc = 0; kc < 8; ++kc) {
      const s16x8 af = *(const s16x8*)(A + (size_t)sl * ASTR + kc * 32 + gq * 8);
      #pragma unroll
      for (int j = 0; j < 2; ++j)
        az[j] = __builtin_amdgcn_mfma_f32_16x16x32_bf16(
            __builtin_bit_cast(bf16x8, af), __builtin_bit_cast(bf16x8, bw[kc][j]),
            az[j], 0, 0, 0);
    }
    // wp1 ships its gate tiles (c,o) to wp0 through the shared buffer
    if (wp == 1 && gq < 2) {
      #pragma unroll
      for (int j = 0; j < 2; ++j)
        #pragma unroll
        for (int rr = 0; rr < 4; ++rr) {
          const int row = gq * 4 + rr;           // local graph 0..7
          xbuf[((gl * 2 + j) * 8 + row) * 16 + sl] = az[j][rr];
        }
    }
    __syncthreads();   // s3: z tiles visible; A reads complete
    if (wp == 0 && gq < 2) {
      #pragma unroll
      for (int rr = 0; rr < 4; ++rr) {
        const int row = gq * 4 + rr;
        if (g0 + row < G) {
          const float u  = az[0][rr] + bU;
          const float f  = az[1][rr] + bF;
          const float c  = xbuf[((gl * 2 + 0) * 8 + row) * 16 + sl] + bC;
          const float o  = xbuf[((gl * 2 + 1) * 8 + row) * 16 + sl] + bO;
          const float mo = mem[row * DD + colB];
          const float mn = sigmoidf_(f) * mo + sigmoidf_(u) * tanhf_(c);
          mem[row * DD + colB] = mn;
          const float cn = sigmoidf_(o) * tanhf_(mn);
          carry[row * DD + colB] = cn;       // f32 state for next score pass
          A[row * ASTR + colB] = f2bf(cn);   // bf16 carry half of next A
        }
      }
    }
    __syncthreads();   // s4: state update visible before next phase A
  }
}

extern "C" void kernel_launch(void* const* d_in, const int* in_sizes, int n_in,
                              void* d_out, int out_size, void* d_ws, size_t ws_size,
                              hipStream_t stream) {
  const float* nf   = (const float*)d_in[0];
  const int*   ind  = (const int*)d_in[1];
  const float* W    = (const float*)d_in[2];
  const float* bias = (const float*)d_in[3];
  int N = in_sizes[1];
  int G = out_size / G2D;   // 25000

  char* ws = (char*)d_ws;
  short* WT  = (short*)ws;                       // 512*256*2 = 262144 B
  int*   seg = (int*)(ws + 262144);              // (G+1)*4 B
  (void)ws_size; (void)n_in;

  seg_kernel<<<(G + 256) / 256, 256, 0, stream>>>(ind, seg, N, G);
  wconv_kernel<<<(G2D * G4D) / 256, 256, 0, stream>>>(W, WT);

  const int SMEM_BYTES = GPB * SLOT * DD * 2     // 131072  nf tile
                       + 16 * ASTR * 2           //   8448  A tile
                       + GPB * DD * 4            //   4096  carry
                       + GPB * DD * 4            //   4096  mem
                       + 8192;                   //   xbuf/zbuf  => 155904
  static bool attr_set = false;
  if (!attr_set) {
    hipFuncSetAttribute(reinterpret_cast<const void*>(fused_kernel),
                        hipFuncAttributeMaxDynamicSharedMemorySize, SMEM_BYTES);
    attr_set = true;
  }
  fused_kernel<<<(G + GPB - 1) / GPB, 1024, SMEM_BYTES, stream>>>(
      nf, seg, WT, bias, (float*)d_out, G);
}

// Round 5
// 1401.479 us; speedup vs baseline: 1.0069x; 1.0031x over previous
//
#include <hip/hip_runtime.h>
#include <stdint.h>

#define DD   128   // D
#define G2D  256   // 2*D
#define G4D  512   // 4*D
#define GPB  8     // graphs per block
#define SLOT 64    // LDS node-row slots per graph
#define ASTR 264   // padded stride (shorts) of A tile

typedef float  f32x4  __attribute__((ext_vector_type(4)));
typedef float  f32x8  __attribute__((ext_vector_type(8)));
typedef short  s16x4  __attribute__((ext_vector_type(4)));
typedef short  s16x8  __attribute__((ext_vector_type(8)));
typedef int    i32x4  __attribute__((ext_vector_type(4)));
typedef __bf16 bf16x8 __attribute__((ext_vector_type(8)));

__device__ __forceinline__ short f2bf(float f) {
  unsigned u = __builtin_bit_cast(unsigned, f);
  u += 0x7FFFu + ((u >> 16) & 1u);   // RNE
  return (short)(u >> 16);
}
__device__ __forceinline__ float bflo(int w_) {
  return __builtin_bit_cast(float, (int)(w_ << 16));
}
__device__ __forceinline__ float bfhi(int w_) {
  return __builtin_bit_cast(float, (int)(w_ & 0xFFFF0000));
}
__device__ __forceinline__ f32x8 unpack8_(i32x4 v) {
  f32x8 x;
  x[0] = bflo(v.x); x[1] = bfhi(v.x);
  x[2] = bflo(v.y); x[3] = bfhi(v.y);
  x[4] = bflo(v.z); x[5] = bfhi(v.z);
  x[6] = bflo(v.w); x[7] = bfhi(v.w);
  return x;
}
__device__ __forceinline__ float sigmoidf_(float x) {
  return 1.f / (1.f + __expf(-x));
}
__device__ __forceinline__ float tanhf_(float x) {
  x = fminf(fmaxf(x, -15.f), 15.f);
  float e = __expf(2.f * x);
  return (e - 1.f) / (e + 1.f);
}

// all-lanes sum within each 16-lane row via DPP row_ror (no LDS round-trips)
template <int CTRL>
__device__ __forceinline__ float dppadd_(float v) {
  const int x = __builtin_amdgcn_update_dpp(
      0, __builtin_bit_cast(int, v), CTRL, 0xF, 0xF, true);
  return v + __builtin_bit_cast(float, x);
}
__device__ __forceinline__ float reduce16(float v) {
  v = dppadd_<0x128>(v);   // row_ror:8
  v = dppadd_<0x124>(v);   // row_ror:4
  v = dppadd_<0x122>(v);   // row_ror:2
  v = dppadd_<0x121>(v);   // row_ror:1
  return v;
}

// Online-softmax row update. MACRO (not lambda with array param!): a C-array
// parameter decays to a pointer and forces xf/acc to scratch (rule #20) —
// that was 275 MB/dispatch of scratch traffic in rounds 3-4.
#define AUPD(XF) do {                                                        \
    float s_ = 0.f;                                                          \
    if (!noscore) {                                                          \
      float a_ = fmaf((XF)[1], cc[1], (XF)[0] * cc[0]);                      \
      float b_ = fmaf((XF)[3], cc[3], (XF)[2] * cc[2]);                      \
      float c_ = fmaf((XF)[5], cc[5], (XF)[4] * cc[4]);                      \
      float d_ = fmaf((XF)[7], cc[7], (XF)[6] * cc[6]);                      \
      s_ = reduce16((a_ + b_) + (c_ + d_));                                  \
    }                                                                        \
    if (s_ > m + 8.f) {                /* rare: raise ref, rescale */        \
      const float sc_ = __expf(m - s_);  /* exp(-huge)=0 on first row */     \
      l *= sc_; acc *= sc_; m = s_;                                          \
    }                                                                        \
    const float p_ = __expf(s_ - m);   /* bounded by e^8 */                  \
    l += p_;                                                                 \
    acc += p_ * (XF);                                                        \
  } while (0)

// seg[g] = lower_bound(ind, g) for g in [0..G]; graph_indicator is sorted.
__global__ void seg_kernel(const int* __restrict__ ind, int* __restrict__ seg,
                           int N, int G) {
  int g = blockIdx.x * blockDim.x + threadIdx.x;
  if (g > G) return;
  int lo = 0, hi = N;
  while (lo < hi) {
    int mid = (lo + hi) >> 1;
    if (ind[mid] < g) lo = mid + 1; else hi = mid;
  }
  seg[g] = lo;
}

// WT[n][k] = bf16(W[k][n]); W is [256,512] fp32, WT is [512,256] bf16
__global__ void wconv_kernel(const float* __restrict__ W, short* __restrict__ WT) {
  int idx = blockIdx.x * blockDim.x + threadIdx.x;  // 131072 threads
  int n = idx & (G4D - 1);
  int k = idx >> 9;
  WT[(size_t)n * G2D + k] = f2bf(W[(size_t)k * G4D + n]);
}

// Fully fused: 8 graphs / 1024-thread block (2 waves per graph), all 8 steps.
__global__ void __launch_bounds__(1024, 4) fused_kernel(
    const float* __restrict__ nf, const int* __restrict__ seg,
    const short* __restrict__ WT, const float* __restrict__ bias,
    float* __restrict__ out, int G) {
  extern __shared__ char smem[];
  short* nfb   = (short*)smem;                                // [GPB][SLOT][DD]
  short* A     = (short*)(smem + GPB * SLOT * DD * 2);        // [16][ASTR]
  float* carry = (float*)(smem + GPB * SLOT * DD * 2 + 16 * ASTR * 2);
  float* mem   = carry + GPB * DD;
  float* xbuf  = mem + GPB * DD;    // 8192 B: softmax partials / z-exchange

  const int t    = threadIdx.x;
  const int w    = t >> 6;
  const int lane = t & 63;
  const int gq   = lane >> 4;      // group / MFMA quad
  const int sl   = lane & 15;      // sub-lane / MFMA l16
  const int gl   = w >> 1;         // local graph id == col-tile id (0..7)
  const int wp   = w & 1;          // wave-in-pair
  const int g0   = blockIdx.x * GPB;
  const int g    = g0 + gl;
  const bool active = (g < G);

  // ---- init ----
  {
    int* az = (int*)A;
    for (int i = t; i < (16 * ASTR) / 2; i += 1024) az[i] = 0;
    if (t < GPB * DD) { mem[t] = 0.f; carry[t] = 0.f; }
  }
  int s0 = 0, n = 0;
  if (active) { s0 = seg[g]; n = seg[g + 1] - s0; }

  // ---- stage rows into LDS (pair covers 4 rows/iter), depth-2 pipeline ----
  short* slot = nfb + gl * (SLOT * DD);
  const int nl = n < SLOT ? n : SLOT;
  {
    const int r4 = (wp << 1) | (lane >> 5);   // 0..3
    const int c  = lane & 31;                 // f32x4 index in row
    f32x4 vc; int rowc = r4; bool okc = rowc < nl;
    if (okc) vc = *((const f32x4*)(nf + (size_t)(s0 + rowc) * DD) + c);
    const int iters = (nl + 3) >> 2;
    for (int i = 0; i < iters; ++i) {
      const int rown = (i + 1) * 4 + r4;
      f32x4 vn; const bool okn = rown < nl;
      if (okn) vn = *((const f32x4*)(nf + (size_t)(s0 + rown) * DD) + c);
      if (okc) {
        s16x4 o;
        o[0] = f2bf(vc.x); o[1] = f2bf(vc.y); o[2] = f2bf(vc.z); o[3] = f2bf(vc.w);
        *(s16x4*)(slot + (size_t)rowc * DD + c * 4) = o;
      }
      vc = vn; rowc = rown; okc = okn;
    }
  }

  // ---- per-wave W cache: 2 gates x 8 kc (64 VGPRs). wp0: u,f; wp1: c,o ----
  s16x8 bw[8][2];
  #pragma unroll
  for (int kc = 0; kc < 8; ++kc)
    #pragma unroll
    for (int j = 0; j < 2; ++j) {
      const int ncol = (wp * 2 + j) * DD + gl * 16 + sl;
      bw[kc][j] = *(const s16x8*)(WT + (size_t)ncol * G2D + kc * 32 + gq * 8);
    }
  const int colB = gl * 16 + sl;
  const float bU = bias[colB],          bF = bias[DD + colB],
              bC = bias[2 * DD + colB], bO = bias[3 * DD + colB];

  __syncthreads();   // staging + zero-init visible to everyone

  #pragma unroll 1
  for (int step = 0; step < 8; ++step) {
    const bool noscore = (step == 0);   // carry==0 -> all scores 0 -> mean pool
    const f32x8 cc = *(const f32x8*)(carry + gl * DD + sl * 8);

    // ============ Phase A: attention readout (pair-split rows) ============
    float m = -1e30f, l = 0.f;
    f32x8 acc = 0.f;
    const int off = wp * 4 + gq;        // row stream id (0..7)

    if (active && n > 0) {
      const short* bp = slot + (size_t)off * DD + sl * 8;
      const int nfull = nl >> 3;
      i32x4 xr;
      if (nfull > 0) xr = *(const i32x4*)bp;
      for (int i = 0; i < nfull; ++i) {
        i32x4 xn = *(const i32x4*)(bp + (size_t)(i + 1) * 8 * DD); // prefetch (overrun benign, in-LDS)
        const f32x8 xf = unpack8_(xr);
        AUPD(xf);
        xr = xn;
      }
      const int rem = nl & 7;
      if (off < rem) {
        const f32x8 xf = unpack8_(*(const i32x4*)(bp + (size_t)nfull * 8 * DD));
        AUPD(xf);
      }
      for (int j = SLOT + off; j < n; j += 8) {     // overflow rows (rare)
        const f32x4* gp = (const f32x4*)(nf + (size_t)(s0 + j) * DD) + sl * 2;
        const f32x4 a = gp[0], b = gp[1];
        f32x8 xf;
        xf[0] = a.x; xf[1] = a.y; xf[2] = a.z; xf[3] = a.w;
        xf[4] = b.x; xf[5] = b.y; xf[6] = b.z; xf[7] = b.w;
        AUPD(xf);
      }
      // intra-wave merge of the 4 groups (xor16, xor32)
      #pragma unroll
      for (int ww = 16; ww <= 32; ww <<= 1) {
        const float m2 = __shfl_xor(m, ww, 64);
        const float l2 = __shfl_xor(l, ww, 64);
        const float M  = fmaxf(m, m2);
        const float e1 = __expf(m - M), e2 = __expf(m2 - M);
        l = l * e1 + l2 * e2;
        f32x8 a2;
        #pragma unroll
        for (int k = 0; k < 8; ++k) a2[k] = __shfl_xor(acc[k], ww, 64);
        acc = acc * e1 + a2 * e2;
        m = M;
      }
    }

    // ---- cross-wave merge through LDS ----
    float* xb = xbuf + (gl * 16 + sl) * 12;
    if (wp == 1 && gq == 0) {
      *(f32x4*)(xb)     = (f32x4){acc[0], acc[1], acc[2], acc[3]};
      *(f32x4*)(xb + 4) = (f32x4){acc[4], acc[5], acc[6], acc[7]};
      xb[8] = m; xb[9] = l;
    }
    __syncthreads();   // s1: partials visible
    if (wp == 0 && gq == 0) {
      const float m2 = xb[8], l2 = xb[9];
      const f32x4 a0 = *(const f32x4*)xb, a1 = *(const f32x4*)(xb + 4);
      f32x8 a2;
      a2[0] = a0.x; a2[1] = a0.y; a2[2] = a0.z; a2[3] = a0.w;
      a2[4] = a1.x; a2[5] = a1.y; a2[6] = a1.z; a2[7] = a1.w;
      const float M  = fmaxf(m, m2);
      const float e1 = __expf(m - M), e2 = __expf(m2 - M);
      const float L  = l * e1 + l2 * e2;
      const float inv = (L > 0.f) ? 1.f / L : 0.f;
      const f32x8 r = (acc * e1 + a2 * e2) * inv;
      s16x8 pk;
      #pragma unroll
      for (int k = 0; k < 8; ++k) pk[k] = f2bf(r[k]);
      *(s16x8*)(A + gl * ASTR + DD + sl * 8) = pk;   // readout half of A row
      if (step == 7 && active) {
        *(f32x4*)(out + (size_t)g * G2D + DD + sl * 8)     = (f32x4){r[0], r[1], r[2], r[3]};
        *(f32x4*)(out + (size_t)g * G2D + DD + sl * 8 + 4) = (f32x4){r[4], r[5], r[6], r[7]};
      }
    }
    if (step == 7) {
      if (wp == 0 && gq == 1 && active) {   // carry half (state after step 6)
        *(f32x4*)(out + (size_t)g * G2D + sl * 8) =
            *(const f32x4*)(carry + gl * DD + sl * 8);
        *(f32x4*)(out + (size_t)g * G2D + sl * 8 + 4) =
            *(const f32x4*)(carry + gl * DD + sl * 8 + 4);
      }
      break;
    }
    __syncthreads();   // s2: A readout visible for MFMA

    // ============ Phase B: batched LSTM via MFMA (2 gates/wave) ============
    f32x4 az[2] = {(f32x4){0.f, 0.f, 0.f, 0.f}, (f32x4){0.f, 0.f, 0.f, 0.f}};
    #pragma unroll
    for (int kc = 0; kc < 8; ++kc) {
      const s16x8 af = *(const s16x8*)(A + (size_t)sl * ASTR + kc * 32 + gq * 8);
      #pragma unroll
      for (int j = 0; j < 2; ++j)
        az[j] = __builtin_amdgcn_mfma_f32_16x16x32_bf16(
            __builtin_bit_cast(bf16x8, af), __builtin_bit_cast(bf16x8, bw[kc][j]),
            az[j], 0, 0, 0);
    }
    // wp1 ships its gate tiles (c,o) to wp0 through the shared buffer
    if (wp == 1 && gq < 2) {
      #pragma unroll
      for (int j = 0; j < 2; ++j)
        #pragma unroll
        for (int rr = 0; rr < 4; ++rr) {
          const int row = gq * 4 + rr;           // local graph 0..7
          xbuf[((gl * 2 + j) * 8 + row) * 16 + sl] = az[j][rr];
        }
    }
    __syncthreads();   // s3: z tiles visible; A reads complete
    if (wp == 0 && gq < 2) {
      #pragma unroll
      for (int rr = 0; rr < 4; ++rr) {
        const int row = gq * 4 + rr;
        if (g0 + row < G) {
          const float u  = az[0][rr] + bU;
          const float f  = az[1][rr] + bF;
          const float c  = xbuf[((gl * 2 + 0) * 8 + row) * 16 + sl] + bC;
          const float o  = xbuf[((gl * 2 + 1) * 8 + row) * 16 + sl] + bO;
          const float mo = mem[row * DD + colB];
          const float mn = sigmoidf_(f) * mo + sigmoidf_(u) * tanhf_(c);
          mem[row * DD + colB] = mn;
          const float cn = sigmoidf_(o) * tanhf_(mn);
          carry[row * DD + colB] = cn;       // f32 state for next score pass
          A[row * ASTR + colB] = f2bf(cn);   // bf16 carry half of next A
        }
      }
    }
    __syncthreads();   // s4: state update visible before next phase A
  }
}

extern "C" void kernel_launch(void* const* d_in, const int* in_sizes, int n_in,
                              void* d_out, int out_size, void* d_ws, size_t ws_size,
                              hipStream_t stream) {
  const float* nf   = (const float*)d_in[0];
  const int*   ind  = (const int*)d_in[1];
  const float* W    = (const float*)d_in[2];
  const float* bias = (const float*)d_in[3];
  int N = in_sizes[1];
  int G = out_size / G2D;   // 25000

  char* ws = (char*)d_ws;
  short* WT  = (short*)ws;                       // 512*256*2 = 262144 B
  int*   seg = (int*)(ws + 262144);              // (G+1)*4 B
  (void)ws_size; (void)n_in;

  seg_kernel<<<(G + 256) / 256, 256, 0, stream>>>(ind, seg, N, G);
  wconv_kernel<<<(G2D * G4D) / 256, 256, 0, stream>>>(W, WT);

  const int SMEM_BYTES = GPB * SLOT * DD * 2     // 131072  nf tile
                       + 16 * ASTR * 2           //   8448  A tile
                       + GPB * DD * 4            //   4096  carry
                       + GPB * DD * 4            //   4096  mem
                       + 8192;                   //   xbuf/zbuf  => 155904
  static bool attr_set = false;
  if (!attr_set) {
    hipFuncSetAttribute(reinterpret_cast<const void*>(fused_kernel),
                        hipFuncAttributeMaxDynamicSharedMemorySize, SMEM_BYTES);
    attr_set = true;
  }
  fused_kernel<<<(G + GPB - 1) / GPB, 1024, SMEM_BYTES, stream>>>(
      nf, seg, WT, bias, (float*)d_out, G);
}